// Round 16
// baseline (822.208 us; speedup 1.0000x reference)
//
#include <hip/hip_runtime.h>
#include <hip/hip_cooperative_groups.h>
#include <stdint.h>

namespace cg = cooperative_groups;

typedef __attribute__((ext_vector_type(8))) short s8_t;    // 8 x bf16 (as short bits)
typedef __attribute__((ext_vector_type(4))) short s4v_t;   // 4 x bf16
typedef __attribute__((ext_vector_type(4))) float f4_t;    // MFMA accumulator
typedef unsigned short u16;

#define V_  50000
#define E_  300
#define EP_ 320
#define H_  512
#define G_  1536
#define O_  64
#define T_  21
#define B_  256
#define S_  128
#define BS_ 32768

// h layout: block-contiguous. c = column 0..511, b = batch row 0..255.
// idx(dir,s,c,b) = (((dir*S+s)*32 + c/16)*256 + b)*16 + c%16
__device__ __forceinline__ size_t hidx(int dir, int s, int c, int b) {
    return ((((size_t)dir * S_ + s) * 32 + (c >> 4)) * B_ + b) * 16 + (c & 15);
}

__device__ __forceinline__ float b2f(u16 u) {
    union { unsigned int u; float f; } v; v.u = ((unsigned int)u) << 16; return v.f;
}
__device__ __forceinline__ u16 f2b(float f) {
    union { float f; unsigned int u; } v; v.f = f;
    unsigned int r = v.u + 0x7fffu + ((v.u >> 16) & 1u);
    return (u16)(r >> 16);
}
__device__ __forceinline__ float fsig(float x) {
    return __builtin_amdgcn_rcpf(1.f + __expf(-x));
}
__device__ __forceinline__ float ftanh(float x) {
    return 1.f - 2.f * __builtin_amdgcn_rcpf(1.f + __expf(2.f * x));
}

// ---------------- weight prep: fp32 -> bf16 ----------------------------------------
__global__ void prep_kernel(const float* wih_f, const float* wih_b,
                            const float* whh_f, const float* whh_b,
                            const float* ner_w, const float* fc_w,
                            u16* wih_bf, u16* whh_bf, u16* nerw_bf, u16* fcw_bf)
{
    const int NW = 3072 * EP_;
    const int NH = 2 * G_ * H_;
    const int NN = 32 * 1024;
    const int NF = O_ * 1024;
    int stride = gridDim.x * blockDim.x;
    for (int i = blockIdx.x * blockDim.x + threadIdx.x; i < NW + NH + NN + NF; i += stride) {
        if (i < NW) {
            int n = i / EP_, k = i % EP_;
            float v = 0.f;
            if (k < E_) v = (n < G_) ? wih_f[n * E_ + k] : wih_b[(n - G_) * E_ + k];
            wih_bf[i] = f2b(v);
        } else if (i < NW + NH) {
            int j = i - NW;
            int d = j / (G_ * H_), r = j % (G_ * H_);
            whh_bf[j] = f2b(d == 0 ? whh_f[r] : whh_b[r]);
        } else if (i < NW + NH + NN) {
            int j = i - NW - NH;
            int t = j / 1024, k = j % 1024;
            nerw_bf[j] = f2b(t < T_ ? ner_w[t * 1024 + k] : 0.f);
        } else {
            int j = i - NW - NH - NN;
            fcw_bf[j] = f2b(fc_w[j]);
        }
    }
}

// ---------------- embedding gather -> xe bf16 [s*B+b][EP_], 8 elems/thread --------
__global__ void gather_kernel(const int* x, const float* emb, u16* xe)
{
    int stride = gridDim.x * blockDim.x;
    const int NU = BS_ * 40;              // units of 8 elements
    for (int u = blockIdx.x * blockDim.x + threadIdx.x; u < NU; u += stride) {
        int m = u / 40, k8 = u % 40;
        int k = k8 * 8;
        int s = m >> 8, b = m & 255;
        short out[8];
        if (k + 8 <= E_) {
            const float* ep = emb + (size_t)x[b * S_ + s] * E_ + k;
            float4 f0 = *(const float4*)(ep);
            float4 f1 = *(const float4*)(ep + 4);
            out[0] = (short)f2b(f0.x); out[1] = (short)f2b(f0.y);
            out[2] = (short)f2b(f0.z); out[3] = (short)f2b(f0.w);
            out[4] = (short)f2b(f1.x); out[5] = (short)f2b(f1.y);
            out[6] = (short)f2b(f1.z); out[7] = (short)f2b(f1.w);
        } else {
            const float* ep = emb + (size_t)x[b * S_ + s] * E_;
#pragma unroll
            for (int j = 0; j < 8; ++j)
                out[j] = (short)f2b((k + j < E_) ? ep[k + j] : 0.f);
        }
        *(s8_t*)(xe + (size_t)m * EP_ + k) = *(s8_t*)out;
    }
}

// ---------------- persistent BiGRU: block-contiguous h, XCD-local groups ----------
// 512 blocks x 256 thr (4 waves), 2/CU. 16 groups of 32 blocks (2 per XCD).
// Sync: producer (each lo wave, after ITS OWN vmcnt(0) drain) writes its flag
// TWICE — plain store (flagP: write-through into the shared XCD L2) + relaxed
// agent atomic (flagA: memory-side, proven-coherent). Consumer polls flagP via
// buffer_inv (L1 invalidate) + volatile load = XCD-L2-local ~300cyc round trip;
// after 8 failed spins it escalates to the flagA atomic poll (guaranteed
// progress even if the L1-invalidate path misbehaves — no R13-style hang).
#define XST 328   // u16 stride for wih LDS rows
__global__ __launch_bounds__(256, 2) void gru_persist(
    const u16* __restrict__ xe, const u16* __restrict__ wih,
    const float* bih_f, const float* bih_b,
    const u16* __restrict__ whh_bf,
    const float* bhh_f, const float* bhh_b,
    u16* h_hi, unsigned int* flagP, unsigned int* flagA, unsigned int* xcnt)
{
    __shared__ u16 sWx[48 * XST];
    __shared__ f4_t red[4][2][64];      // [acc][wpair][lane] : 8 KB
    __shared__ unsigned int role_sh[2];

    cg::grid_group grid = cg::this_grid();
    int tid = threadIdx.x, l = tid & 63, wid = tid >> 6;   // wid 0..3

    if (tid == 0) {
        unsigned int xcc = __builtin_amdgcn_s_getreg((7u << 11) | 20u) & 7u;
        unsigned int slot = __hip_atomic_fetch_add(&xcnt[xcc], 1u,
                                __ATOMIC_RELAXED, __HIP_MEMORY_SCOPE_AGENT);
        role_sh[0] = xcc; role_sh[1] = slot;
    }
    grid.sync();
    bool fast = true;
    for (int i = 0; i < 8; ++i)
        fast = fast && (__hip_atomic_load(&xcnt[i], __ATOMIC_RELAXED,
                            __HIP_MEMORY_SCOPE_AGENT) == 64u);
    int g, hs;
    if (fast) {
        unsigned int xcc = role_sh[0], slot = role_sh[1];
        g  = (int)(xcc * 2 + (slot >> 5));   // two groups per XCD
        hs = (int)(slot & 31);
    } else {
        g = blockIdx.x >> 5; hs = blockIdx.x & 31;
    }
    int dir = g >> 3, bt = g & 7;         // bt: 8 slabs of 32 rows per dir
    int wpair = wid & 1;
    int khi   = wid >> 1;                 // 0 = K-low waves, 1 = K-high waves
    int r0  = bt * 32 + wpair * 16;
    int hc0 = hs * 16;
    int lr = l & 15, lk = (l >> 4) * 8;
    int koff_h = khi ? 256 : 0;
    int koff_x = khi ? 160 : 0;

    // ---- stage Wx slice into LDS (once) ----
    for (int idx = tid; idx < 48 * 40; idx += 256) {
        int rr = idx / 40, ck = (idx % 40) * 8;
        int gcol = (rr >> 4) * H_ + hc0 + (rr & 15);
        size_t goff = ((size_t)dir * G_ + gcol) * (size_t)EP_ + ck;
        *(s8_t*)&sWx[rr * XST + ck] = *(const s8_t*)&wih[goff];
    }

    // ---- W_hh B-fragments -> registers (once): 3 gates x 8 k-chunks x 16B ----
    s8_t Bh[3][8];
#pragma unroll
    for (int c = 0; c < 3; ++c)
#pragma unroll
        for (int kk = 0; kk < 8; ++kk)
            Bh[c][kk] = *(const s8_t*)&whh_bf[
                ((size_t)dir * G_ + c * H_ + hc0 + lr) * (size_t)H_ + koff_h + lk + kk * 32];
    __syncthreads();

    int lc = l & 15, lr4 = (l >> 4) * 4;
    int hc = hc0 + lc;
    const float* bih = dir ? bih_b : bih_f;
    const float* bhh = dir ? bhh_b : bhh_f;
    float br  = bih[hc] + bhh[hc];
    float bz  = bih[H_ + hc] + bhh[H_ + hc];
    float bxn = bih[2 * H_ + hc];
    float bhn = bhh[2 * H_ + hc];
    float hstate[4] = {0.f, 0.f, 0.f, 0.f};

    f4_t xac[3];                          // r, z, xn partials (this wave's K-half)
    auto xgemm = [&](int ttx) {
#pragma unroll
        for (int c = 0; c < 3; ++c) xac[c] = (f4_t){0.f, 0.f, 0.f, 0.f};
        const u16* xp = xe + ((size_t)ttx * B_ + r0 + lr) * EP_ + koff_x + lk;
#pragma unroll
        for (int kk = 0; kk < 5; ++kk) {
            s8_t ax = *(const s8_t*)(xp + kk * 32);
#pragma unroll
            for (int c = 0; c < 3; ++c) {
                s8_t bx = *(const s8_t*)&sWx[(c * 16 + lr) * XST + koff_x + lk + kk * 32];
                xac[c] = __builtin_amdgcn_mfma_f32_16x16x32_bf16(ax, bx, xac[c], 0, 0, 0);
            }
        }
    };

    xgemm(dir ? (S_ - 1) : 0);            // prologue: x-part for t=0

#pragma unroll 1
    for (int t = 0; t < S_; ++t) {
        int tt = dir ? (S_ - 1 - t) : t;

        if (t > 0) {
            if (fast) {
                // per-wave wait: the 16 producers of THIS wave's (K-half, row-half).
                int fi = g * 64 + (khi * 16 + (l & 15)) * 2 + wpair;
                const unsigned int* fpP = flagP + fi;
                const unsigned int* fpA = flagA + fi;
                unsigned int tgt = (unsigned int)t;
                int spin = 0;
                for (;;) {
                    unsigned int v = tgt;
                    if (l < 16) {
                        if (spin <= 8) {
                            asm volatile("buffer_inv" ::: "memory");
                            v = *(volatile const unsigned int*)fpP;
                        } else {
                            v = __hip_atomic_load(fpA, __ATOMIC_RELAXED,
                                                  __HIP_MEMORY_SCOPE_AGENT);
                        }
                    }
                    if (__all((int)(v >= tgt))) break;
                    ++spin;
                    if (spin > 4) __builtin_amdgcn_s_sleep(1);
                }
                asm volatile("" ::: "memory");   // don't hoist h-loads above the poll
            } else {
                __threadfence();
                grid.sync();
                __threadfence();
            }
        }

        f4_t ahn = {0.f, 0.f, 0.f, 0.f};  // recurrent n-gate partial
        if (t > 0) {
            int prev = dir ? (tt + 1) : (tt - 1);
            const u16* hb = h_hi + hidx(dir, prev, koff_h + lk, r0 + lr);
            s8_t ah[8];
#pragma unroll
            for (int kk = 0; kk < 8; ++kk)
                ah[kk] = *(const s8_t*)(hb + (size_t)kk * 2 * B_ * 16);
#pragma unroll
            for (int kk = 0; kk < 8; ++kk) {
                xac[0] = __builtin_amdgcn_mfma_f32_16x16x32_bf16(ah[kk], Bh[0][kk], xac[0], 0, 0, 0);
                xac[1] = __builtin_amdgcn_mfma_f32_16x16x32_bf16(ah[kk], Bh[1][kk], xac[1], 0, 0, 0);
                ahn    = __builtin_amdgcn_mfma_f32_16x16x32_bf16(ah[kk], Bh[2][kk], ahn,    0, 0, 0);
            }
        }

        // ---- cross-K reduction: hi waves publish partials, lo waves finish ----
        if (khi) {
            red[0][wpair][l] = xac[0];
            red[1][wpair][l] = xac[1];
            red[2][wpair][l] = xac[2];
            red[3][wpair][l] = ahn;
        }
        __syncthreads();
        if (!khi) {
            f4_t q0 = red[0][wpair][l];
            f4_t q1 = red[1][wpair][l];
            f4_t q2 = red[2][wpair][l];
            f4_t q3 = red[3][wpair][l];
            u16* hw = h_hi + hidx(dir, tt, hc0 + lc, 0);   // + row*16 below
#pragma unroll
            for (int r = 0; r < 4; ++r) {
                int row = r0 + lr4 + r;
                float pre_r = xac[0][r] + q0[r] + br;
                float pre_z = xac[1][r] + q1[r] + bz;
                float xn  = xac[2][r] + q2[r] + bxn;
                float hnv = ahn[r] + q3[r] + bhn;
                float rg = fsig(pre_r);
                float zg = fsig(pre_z);
                float ng = ftanh(xn + rg * hnv);
                float hnew = (1.f - zg) * ng + zg * hstate[r];
                hstate[r] = hnew;
                hw[(size_t)row * 16] = f2b(hnew);
            }
            if (fast && t < S_ - 1) {
                // drain OUR 16x16 stores, then signal both flag tiers.
                asm volatile("s_waitcnt vmcnt(0)" ::: "memory");
                if (l == 0) {
                    int fi = g * 64 + hs * 2 + wpair;
                    *(volatile unsigned int*)(flagP + fi) = (unsigned int)(t + 1);
                    __hip_atomic_store(flagA + fi, (unsigned int)(t + 1),
                                       __ATOMIC_RELAXED, __HIP_MEMORY_SCOPE_AGENT);
                }
            }
        }

        __syncthreads();   // WAR on red buffer (+ block-wide store drain on slow path)
        if (t < S_ - 1)
            xgemm(dir ? (S_ - 2 - t) : (t + 1));   // overlap next x-part with wait
    }
}

// ---------------- fused scores + emissions + y=fc@h: ONE pass over h --------------
__global__ __launch_bounds__(256) void rowpass_kernel(const u16* h_hi, const u16* nerw,
                                                      const float* ner_b, const u16* fcw,
                                                      const float* attn_w, const float* attn_b,
                                                      float* em, float* scores, float* y)
{
    int tid = threadIdx.x, l = tid & 63, wid = tid >> 6;
    int rb = blockIdx.x * 64 + wid * 16;
    int lr = l & 15, lk = (l >> 4) * 8;
    f4_t acc[2] = {};
    f4_t accY[4] = {};
    float sacc = 0.f;
    for (int kk = 0; kk < 32; ++kk) {
        int k0 = kk * 32 + lk;
        int dir = k0 >> 9, c = k0 & 511;
        int row = rb + lr;                 // global (s,b): s=row>>8, b=row&255
        s8_t a = *(const s8_t*)(h_hi + hidx(dir, row >> 8, c, row & 255));
        s8_t b0 = *(const s8_t*)(nerw + (size_t)lr * 1024 + k0);
        s8_t b1 = *(const s8_t*)(nerw + (size_t)(16 + lr) * 1024 + k0);
        acc[0] = __builtin_amdgcn_mfma_f32_16x16x32_bf16(a, b0, acc[0], 0, 0, 0);
        acc[1] = __builtin_amdgcn_mfma_f32_16x16x32_bf16(a, b1, acc[1], 0, 0, 0);
#pragma unroll
        for (int f = 0; f < 4; ++f) {
            s8_t bf = *(const s8_t*)(fcw + (size_t)(f * 16 + lr) * 1024 + k0);
            accY[f] = __builtin_amdgcn_mfma_f32_16x16x32_bf16(a, bf, accY[f], 0, 0, 0);
        }
        float4 aw0 = *(const float4*)(attn_w + k0);
        float4 aw1 = *(const float4*)(attn_w + k0 + 4);
        sacc += b2f((u16)a[0]) * aw0.x + b2f((u16)a[1]) * aw0.y
              + b2f((u16)a[2]) * aw0.z + b2f((u16)a[3]) * aw0.w
              + b2f((u16)a[4]) * aw1.x + b2f((u16)a[5]) * aw1.y
              + b2f((u16)a[6]) * aw1.z + b2f((u16)a[7]) * aw1.w;
    }
    sacc += __shfl_down(sacc, 32);
    sacc += __shfl_down(sacc, 16);
    if (l < 16) {
        int row = rb + l;
        scores[(row & 255) * S_ + (row >> 8)] = sacc + attn_b[0];
    }
    int lc = l & 15, lr4 = (l >> 4) * 4;
#pragma unroll
    for (int f = 0; f < 2; ++f) {
        int tcol = f * 16 + lc;
        if (tcol < T_) {
            float nb = ner_b[tcol];
#pragma unroll
            for (int r = 0; r < 4; ++r) {
                int row = rb + lr4 + r;
                int s = row >> 8, bb = row & 255;
                em[((size_t)bb * S_ + s) * T_ + tcol] = acc[f][r] + nb;
            }
        }
    }
#pragma unroll
    for (int f = 0; f < 4; ++f) {
        int tcol = f * 16 + lc;
#pragma unroll
        for (int r = 0; r < 4; ++r) {
            int row = rb + lr4 + r;
            y[(size_t)row * O_ + tcol] = accY[f][r];
        }
    }
}

// ---------------- softmax + intent from y (no second h pass) ----------------------
__global__ __launch_bounds__(256) void attn_kernel(const float* scores, const float* y,
                                                   const float* fc_b, float* out)
{
    __shared__ float sc[S_];
    __shared__ float tmp[S_];
    __shared__ float part[4][O_];
    int b = blockIdx.x, tid = threadIdx.x;
    if (tid < S_) sc[tid] = scores[b * S_ + tid];
    __syncthreads();
    if (tid < S_) tmp[tid] = sc[tid];
    __syncthreads();
    for (int st = 64; st > 0; st >>= 1) {
        if (tid < st) tmp[tid] = fmaxf(tmp[tid], tmp[tid + st]);
        __syncthreads();
    }
    float mx = tmp[0];
    __syncthreads();
    if (tid < S_) { sc[tid] = __expf(sc[tid] - mx); tmp[tid] = sc[tid]; }
    __syncthreads();
    for (int st = 64; st > 0; st >>= 1) {
        if (tid < st) tmp[tid] += tmp[tid + st];
        __syncthreads();
    }
    float inv = 1.f / tmp[0];
    __syncthreads();
    if (tid < S_) sc[tid] *= inv;
    __syncthreads();

    int o = tid & 63, q = tid >> 6;
    float acc = 0.f;
    for (int s = q * 32; s < q * 32 + 32; ++s)
        acc += sc[s] * y[((size_t)s * B_ + b) * O_ + o];
    part[q][o] = acc;
    __syncthreads();
    if (tid < O_)
        out[b * O_ + tid] = part[0][tid] + part[1][tid] + part[2][tid] + part[3][tid]
                          + fc_b[tid];
}

// ---------------- CRF numerator: one block per batch, lane-parallel over s --------
__global__ __launch_bounds__(64) void num_kernel(const int* tags, const float* em,
                                                 const float* cstart, const float* cend,
                                                 const float* ctrans, float* numv)
{
    int b = blockIdx.x, l = threadIdx.x;
    const int* tg = tags + b * S_;
    float acc = 0.f;
#pragma unroll
    for (int q = 0; q < 2; ++q) {
        int s = l + q * 64;
        int tc = tg[s];
        acc += em[((size_t)b * S_ + s) * T_ + tc];
        if (s > 0) acc += ctrans[tg[s - 1] * T_ + tc];
    }
#pragma unroll
    for (int off = 32; off; off >>= 1) acc += __shfl_down(acc, off);
    if (l == 0) numv[b] = acc + cstart[tg[0]] + cend[tg[S_ - 1]];
}

// ---------------- CRF forward (logZ): two batch elems per block (width-32 segs) ---
__global__ __launch_bounds__(64) void crf2_kernel(const float* em, const float* cstart,
                                                  const float* cend, const float* ctrans,
                                                  float* logZ)
{
    int l = threadIdx.x & 31;
    int b = blockIdx.x * 2 + (threadIdx.x >> 5);
    bool act = l < T_;
    float E[T_];
#pragma unroll
    for (int i = 0; i < T_; ++i) E[i] = act ? __expf(ctrans[i * T_ + l]) : 0.f;
    const float* eb = em + (size_t)b * S_ * T_;
    float sc = act ? (cstart[l] + eb[l]) : -1e30f;
#pragma unroll 1
    for (int s = 1; s < S_; ++s) {
        float emv = act ? eb[s * T_ + l] : 0.f;
        float m = sc;
#pragma unroll
        for (int off = 16; off; off >>= 1) m = fmaxf(m, __shfl_xor(m, off, 32));
        float e = act ? __expf(sc - m) : 0.f;
        float sum = 0.f;
#pragma unroll
        for (int i = 0; i < T_; ++i) sum += __shfl(e, i, 32) * E[i];
        sc = act ? (m + __logf(sum) + emv) : -1e30f;
    }
    float fin = act ? (sc + cend[l]) : -1e30f;
    float m = fin;
#pragma unroll
    for (int off = 16; off; off >>= 1) m = fmaxf(m, __shfl_xor(m, off, 32));
    float z = act ? __expf(fin - m) : 0.f;
#pragma unroll
    for (int off = 16; off; off >>= 1) z += __shfl_xor(z, off, 32);
    if (l == 0) logZ[b] = m + __logf(z);
}

// ---------------- final loss ------------------------------------------------------
__global__ __launch_bounds__(256) void loss_kernel(const float* numv, const float* logZ,
                                                   float* out)
{
    __shared__ float red[B_];
    int t = threadIdx.x;
    red[t] = numv[t] - logZ[t];
    __syncthreads();
    for (int st = 128; st > 0; st >>= 1) {
        if (t < st) red[t] += red[t + st];
        __syncthreads();
    }
    if (t == 0) out[16384] = -red[0] / (float)B_;
}

extern "C" void kernel_launch(void* const* d_in, const int* in_sizes, int n_in,
                              void* d_out, int out_size, void* d_ws, size_t ws_size,
                              hipStream_t stream)
{
    const int*   x      = (const int*)  d_in[0];
    const int*   tags   = (const int*)  d_in[1];
    const float* emb    = (const float*)d_in[3];
    const float* wih_f  = (const float*)d_in[4];
    const float* whh_f  = (const float*)d_in[5];
    const float* bih_f  = (const float*)d_in[6];
    const float* bhh_f  = (const float*)d_in[7];
    const float* wih_b  = (const float*)d_in[8];
    const float* whh_b  = (const float*)d_in[9];
    const float* bih_b  = (const float*)d_in[10];
    const float* bhh_b  = (const float*)d_in[11];
    const float* attn_w = (const float*)d_in[12];
    const float* attn_b = (const float*)d_in[13];
    const float* fc_w   = (const float*)d_in[14];
    const float* fc_b   = (const float*)d_in[15];
    const float* ner_w  = (const float*)d_in[16];
    const float* ner_b  = (const float*)d_in[17];
    const float* cstart = (const float*)d_in[18];
    const float* cend   = (const float*)d_in[19];
    const float* ctrans = (const float*)d_in[20];
    float* out = (float*)d_out;

    char* p = (char*)d_ws;
    auto alloc = [&](size_t bytes) { void* r = (void*)p; p += (bytes + 255) & ~(size_t)255; return r; };
    u16* wih_bf  = (u16*)alloc((size_t)3072 * EP_ * 2);
    u16* whh_bf  = (u16*)alloc((size_t)2 * G_ * H_ * 2);
    u16* nerw_bf = (u16*)alloc((size_t)32 * 1024 * 2);
    u16* fcw_bf  = (u16*)alloc((size_t)O_ * 1024 * 2);
    u16* xe      = (u16*)alloc((size_t)BS_ * EP_ * 2);
    u16* h_hi    = (u16*)alloc((size_t)2 * BS_ * H_ * 2);
    unsigned int* flagP = (unsigned int*)alloc(16 * 64 * 4);
    unsigned int* flagA = (unsigned int*)alloc(16 * 64 * 4);
    unsigned int* xcnt  = (unsigned int*)alloc(64);
    float* scores= (float*)alloc((size_t)BS_ * 4);
    float* y     = (float*)alloc((size_t)BS_ * O_ * 4);      // 8 MB
    float* em    = (float*)alloc((size_t)B_ * S_ * T_ * 4);
    float* numv  = (float*)alloc(1024);
    float* logZ  = (float*)alloc(1024);

    hipMemsetAsync(flagP, 0, 16 * 64 * 4, stream);
    hipMemsetAsync(flagA, 0, 16 * 64 * 4, stream);
    hipMemsetAsync(xcnt, 0, 64, stream);

    hipLaunchKernelGGL(prep_kernel, dim3(2048), dim3(256), 0, stream,
                       wih_f, wih_b, whh_f, whh_b, ner_w, fc_w,
                       wih_bf, whh_bf, nerw_bf, fcw_bf);
    hipLaunchKernelGGL(gather_kernel, dim3(2048), dim3(256), 0, stream, x, emb, xe);

    void* args[] = { &xe, &wih_bf, &bih_f, &bih_b, &whh_bf, &bhh_f, &bhh_b,
                     &h_hi, &flagP, &flagA, &xcnt };
    hipLaunchCooperativeKernel((const void*)gru_persist, dim3(512), dim3(256), args, 0, stream);

    hipLaunchKernelGGL(rowpass_kernel, dim3(BS_ / 64), dim3(256), 0, stream,
                       h_hi, nerw_bf, ner_b, fcw_bf, attn_w, attn_b, em, scores, y);
    hipLaunchKernelGGL(attn_kernel, dim3(B_), dim3(256), 0, stream, scores, y, fc_b, out);
    hipLaunchKernelGGL(num_kernel, dim3(B_), dim3(64), 0, stream, tags, em, cstart, cend, ctrans, numv);
    hipLaunchKernelGGL(crf2_kernel, dim3(B_ / 2), dim3(64), 0, stream, em, cstart, cend, ctrans, logZ);
    hipLaunchKernelGGL(loss_kernel, dim3(1), dim3(256), 0, stream, numv, logZ, out);
}

// Round 17
// 701.674 us; speedup vs baseline: 1.1718x; 1.1718x over previous
//
#include <hip/hip_runtime.h>
#include <hip/hip_cooperative_groups.h>
#include <stdint.h>

namespace cg = cooperative_groups;

typedef __attribute__((ext_vector_type(8))) short s8_t;    // 8 x bf16 (as short bits)
typedef __attribute__((ext_vector_type(4))) short s4v_t;   // 4 x bf16
typedef __attribute__((ext_vector_type(4))) float f4_t;    // MFMA accumulator
typedef unsigned short u16;

#define V_  50000
#define E_  300
#define EP_ 320
#define H_  512
#define G_  1536
#define O_  64
#define T_  21
#define B_  256
#define S_  128
#define BS_ 32768

// h layout: block-contiguous. c = column 0..511, b = batch row 0..255.
// idx(dir,s,c,b) = (((dir*S+s)*32 + c/16)*256 + b)*16 + c%16
__device__ __forceinline__ size_t hidx(int dir, int s, int c, int b) {
    return ((((size_t)dir * S_ + s) * 32 + (c >> 4)) * B_ + b) * 16 + (c & 15);
}

__device__ __forceinline__ float b2f(u16 u) {
    union { unsigned int u; float f; } v; v.u = ((unsigned int)u) << 16; return v.f;
}
__device__ __forceinline__ u16 f2b(float f) {
    union { float f; unsigned int u; } v; v.f = f;
    unsigned int r = v.u + 0x7fffu + ((v.u >> 16) & 1u);
    return (u16)(r >> 16);
}
__device__ __forceinline__ float fsig(float x) {
    return __builtin_amdgcn_rcpf(1.f + __expf(-x));
}
__device__ __forceinline__ float ftanh(float x) {
    return 1.f - 2.f * __builtin_amdgcn_rcpf(1.f + __expf(2.f * x));
}

// ---------------- weight prep: fp32 -> bf16 ----------------------------------------
__global__ void prep_kernel(const float* wih_f, const float* wih_b,
                            const float* whh_f, const float* whh_b,
                            const float* ner_w, const float* fc_w,
                            u16* wih_bf, u16* whh_bf, u16* nerw_bf, u16* fcw_bf)
{
    const int NW = 3072 * EP_;
    const int NH = 2 * G_ * H_;
    const int NN = 32 * 1024;
    const int NF = O_ * 1024;
    int stride = gridDim.x * blockDim.x;
    for (int i = blockIdx.x * blockDim.x + threadIdx.x; i < NW + NH + NN + NF; i += stride) {
        if (i < NW) {
            int n = i / EP_, k = i % EP_;
            float v = 0.f;
            if (k < E_) v = (n < G_) ? wih_f[n * E_ + k] : wih_b[(n - G_) * E_ + k];
            wih_bf[i] = f2b(v);
        } else if (i < NW + NH) {
            int j = i - NW;
            int d = j / (G_ * H_), r = j % (G_ * H_);
            whh_bf[j] = f2b(d == 0 ? whh_f[r] : whh_b[r]);
        } else if (i < NW + NH + NN) {
            int j = i - NW - NH;
            int t = j / 1024, k = j % 1024;
            nerw_bf[j] = f2b(t < T_ ? ner_w[t * 1024 + k] : 0.f);
        } else {
            int j = i - NW - NH - NN;
            fcw_bf[j] = f2b(fc_w[j]);
        }
    }
}

// ---------------- embedding gather -> xe bf16 [s*B+b][EP_], 8 elems/thread --------
__global__ void gather_kernel(const int* x, const float* emb, u16* xe)
{
    int stride = gridDim.x * blockDim.x;
    const int NU = BS_ * 40;              // units of 8 elements
    for (int u = blockIdx.x * blockDim.x + threadIdx.x; u < NU; u += stride) {
        int m = u / 40, k8 = u % 40;
        int k = k8 * 8;
        int s = m >> 8, b = m & 255;
        short out[8];
        if (k + 8 <= E_) {
            const float* ep = emb + (size_t)x[b * S_ + s] * E_ + k;
            float4 f0 = *(const float4*)(ep);
            float4 f1 = *(const float4*)(ep + 4);
            out[0] = (short)f2b(f0.x); out[1] = (short)f2b(f0.y);
            out[2] = (short)f2b(f0.z); out[3] = (short)f2b(f0.w);
            out[4] = (short)f2b(f1.x); out[5] = (short)f2b(f1.y);
            out[6] = (short)f2b(f1.z); out[7] = (short)f2b(f1.w);
        } else {
            const float* ep = emb + (size_t)x[b * S_ + s] * E_;
#pragma unroll
            for (int j = 0; j < 8; ++j)
                out[j] = (short)f2b((k + j < E_) ? ep[k + j] : 0.f);
        }
        *(s8_t*)(xe + (size_t)m * EP_ + k) = *(s8_t*)out;
    }
}

// ---------------- persistent BiGRU: block-contiguous h, XCD-local groups ----------
// 512 blocks x 256 thr (4 waves), 2/CU. 16 groups of 32 blocks (2 per XCD). Wave
// pairs split K; W_hh B-frags in regs. Sync (R15 config — the measured floor):
// each lo wave drains ITS OWN h stores (vmcnt 0) then signals its (hs,wpair) flag
// via relaxed agent atomic store; consumers poll the 16 producers of (their
// K-half, row-half) with relaxed agent atomic loads. Six sync variants (R6-R16)
// bracket this same ~4.5us/step floor: agent atomics are serviced memory-side,
// and they are the only coherent polling primitive (sc0/plain polls hang or
// regress). Fallback if placement != 64/XCD: per-step grid.sync.
#define XST 328   // u16 stride for wih LDS rows
__global__ __launch_bounds__(256, 2) void gru_persist(
    const u16* __restrict__ xe, const u16* __restrict__ wih,
    const float* bih_f, const float* bih_b,
    const u16* __restrict__ whh_bf,
    const float* bhh_f, const float* bhh_b,
    u16* h_hi, unsigned int* flag, unsigned int* xcnt)
{
    __shared__ u16 sWx[48 * XST];
    __shared__ f4_t red[4][2][64];      // [acc][wpair][lane] : 8 KB
    __shared__ unsigned int role_sh[2];

    cg::grid_group grid = cg::this_grid();
    int tid = threadIdx.x, l = tid & 63, wid = tid >> 6;   // wid 0..3

    if (tid == 0) {
        unsigned int xcc = __builtin_amdgcn_s_getreg((7u << 11) | 20u) & 7u;
        unsigned int slot = __hip_atomic_fetch_add(&xcnt[xcc], 1u,
                                __ATOMIC_RELAXED, __HIP_MEMORY_SCOPE_AGENT);
        role_sh[0] = xcc; role_sh[1] = slot;
    }
    grid.sync();
    bool fast = true;
    for (int i = 0; i < 8; ++i)
        fast = fast && (__hip_atomic_load(&xcnt[i], __ATOMIC_RELAXED,
                            __HIP_MEMORY_SCOPE_AGENT) == 64u);
    int g, hs;
    if (fast) {
        unsigned int xcc = role_sh[0], slot = role_sh[1];
        g  = (int)(xcc * 2 + (slot >> 5));   // two groups per XCD
        hs = (int)(slot & 31);
    } else {
        g = blockIdx.x >> 5; hs = blockIdx.x & 31;
    }
    int dir = g >> 3, bt = g & 7;         // bt: 8 slabs of 32 rows per dir
    int wpair = wid & 1;
    int khi   = wid >> 1;                 // 0 = K-low waves, 1 = K-high waves
    int r0  = bt * 32 + wpair * 16;
    int hc0 = hs * 16;
    int lr = l & 15, lk = (l >> 4) * 8;
    int koff_h = khi ? 256 : 0;
    int koff_x = khi ? 160 : 0;

    // ---- stage Wx slice into LDS (once) ----
    for (int idx = tid; idx < 48 * 40; idx += 256) {
        int rr = idx / 40, ck = (idx % 40) * 8;
        int gcol = (rr >> 4) * H_ + hc0 + (rr & 15);
        size_t goff = ((size_t)dir * G_ + gcol) * (size_t)EP_ + ck;
        *(s8_t*)&sWx[rr * XST + ck] = *(const s8_t*)&wih[goff];
    }

    // ---- W_hh B-fragments -> registers (once): 3 gates x 8 k-chunks x 16B ----
    s8_t Bh[3][8];
#pragma unroll
    for (int c = 0; c < 3; ++c)
#pragma unroll
        for (int kk = 0; kk < 8; ++kk)
            Bh[c][kk] = *(const s8_t*)&whh_bf[
                ((size_t)dir * G_ + c * H_ + hc0 + lr) * (size_t)H_ + koff_h + lk + kk * 32];
    __syncthreads();

    int lc = l & 15, lr4 = (l >> 4) * 4;
    int hc = hc0 + lc;
    const float* bih = dir ? bih_b : bih_f;
    const float* bhh = dir ? bhh_b : bhh_f;
    float br  = bih[hc] + bhh[hc];
    float bz  = bih[H_ + hc] + bhh[H_ + hc];
    float bxn = bih[2 * H_ + hc];
    float bhn = bhh[2 * H_ + hc];
    float hstate[4] = {0.f, 0.f, 0.f, 0.f};

    f4_t xac[3];                          // r, z, xn partials (this wave's K-half)
    auto xgemm = [&](int ttx) {
#pragma unroll
        for (int c = 0; c < 3; ++c) xac[c] = (f4_t){0.f, 0.f, 0.f, 0.f};
        const u16* xp = xe + ((size_t)ttx * B_ + r0 + lr) * EP_ + koff_x + lk;
#pragma unroll
        for (int kk = 0; kk < 5; ++kk) {
            s8_t ax = *(const s8_t*)(xp + kk * 32);
#pragma unroll
            for (int c = 0; c < 3; ++c) {
                s8_t bx = *(const s8_t*)&sWx[(c * 16 + lr) * XST + koff_x + lk + kk * 32];
                xac[c] = __builtin_amdgcn_mfma_f32_16x16x32_bf16(ax, bx, xac[c], 0, 0, 0);
            }
        }
    };

    xgemm(dir ? (S_ - 1) : 0);            // prologue: x-part for t=0

#pragma unroll 1
    for (int t = 0; t < S_; ++t) {
        int tt = dir ? (S_ - 1 - t) : t;

        if (t > 0) {
            if (fast) {
                // per-wave wait: the 16 producers of THIS wave's (K-half, row-half).
                const unsigned int* fp = flag + g * 64 + (khi * 16 + (l & 15)) * 2 + wpair;
                unsigned int tgt = (unsigned int)t;
                int spin = 0;
                for (;;) {
                    unsigned int v = tgt;
                    if (l < 16) v = __hip_atomic_load(fp, __ATOMIC_RELAXED,
                                                      __HIP_MEMORY_SCOPE_AGENT);
                    if (__all((int)(v >= tgt))) break;
                    if (++spin > 2) __builtin_amdgcn_s_sleep(1);
                }
                asm volatile("" ::: "memory");   // don't hoist h-loads above the poll
            } else {
                __threadfence();
                grid.sync();
                __threadfence();
            }
        }

        f4_t ahn = {0.f, 0.f, 0.f, 0.f};  // recurrent n-gate partial
        if (t > 0) {
            int prev = dir ? (tt + 1) : (tt - 1);
            const u16* hb = h_hi + hidx(dir, prev, koff_h + lk, r0 + lr);
            s8_t ah[8];
#pragma unroll
            for (int kk = 0; kk < 8; ++kk)
                ah[kk] = *(const s8_t*)(hb + (size_t)kk * 2 * B_ * 16);
#pragma unroll
            for (int kk = 0; kk < 8; ++kk) {
                xac[0] = __builtin_amdgcn_mfma_f32_16x16x32_bf16(ah[kk], Bh[0][kk], xac[0], 0, 0, 0);
                xac[1] = __builtin_amdgcn_mfma_f32_16x16x32_bf16(ah[kk], Bh[1][kk], xac[1], 0, 0, 0);
                ahn    = __builtin_amdgcn_mfma_f32_16x16x32_bf16(ah[kk], Bh[2][kk], ahn,    0, 0, 0);
            }
        }

        // ---- cross-K reduction: hi waves publish partials, lo waves finish ----
        if (khi) {
            red[0][wpair][l] = xac[0];
            red[1][wpair][l] = xac[1];
            red[2][wpair][l] = xac[2];
            red[3][wpair][l] = ahn;
        }
        __syncthreads();
        if (!khi) {
            f4_t q0 = red[0][wpair][l];
            f4_t q1 = red[1][wpair][l];
            f4_t q2 = red[2][wpair][l];
            f4_t q3 = red[3][wpair][l];
            u16* hw = h_hi + hidx(dir, tt, hc0 + lc, 0);   // + row*16 below
#pragma unroll
            for (int r = 0; r < 4; ++r) {
                int row = r0 + lr4 + r;
                float pre_r = xac[0][r] + q0[r] + br;
                float pre_z = xac[1][r] + q1[r] + bz;
                float xn  = xac[2][r] + q2[r] + bxn;
                float hnv = ahn[r] + q3[r] + bhn;
                float rg = fsig(pre_r);
                float zg = fsig(pre_z);
                float ng = ftanh(xn + rg * hnv);
                float hnew = (1.f - zg) * ng + zg * hstate[r];
                hstate[r] = hnew;
                hw[(size_t)row * 16] = f2b(hnew);
            }
            if (fast && t < S_ - 1) {
                // this wave's 16 rows x 16 cols are all that (hs, wpair) consumers
                // need: drain OUR stores only, then signal immediately.
                asm volatile("s_waitcnt vmcnt(0)" ::: "memory");
                if (l == 0)
                    __hip_atomic_store(flag + g * 64 + hs * 2 + wpair, (unsigned int)(t + 1),
                                       __ATOMIC_RELAXED, __HIP_MEMORY_SCOPE_AGENT);
            }
        }

        __syncthreads();   // WAR on red buffer (+ block-wide store drain on slow path)
        if (t < S_ - 1)
            xgemm(dir ? (S_ - 2 - t) : (t + 1));   // overlap next x-part with wait
    }
}

// ---------------- fused scores + emissions + y=fc@h: ONE pass over h --------------
__global__ __launch_bounds__(256) void rowpass_kernel(const u16* h_hi, const u16* nerw,
                                                      const float* ner_b, const u16* fcw,
                                                      const float* attn_w, const float* attn_b,
                                                      float* em, float* scores, float* y)
{
    int tid = threadIdx.x, l = tid & 63, wid = tid >> 6;
    int rb = blockIdx.x * 64 + wid * 16;
    int lr = l & 15, lk = (l >> 4) * 8;
    f4_t acc[2] = {};
    f4_t accY[4] = {};
    float sacc = 0.f;
    for (int kk = 0; kk < 32; ++kk) {
        int k0 = kk * 32 + lk;
        int dir = k0 >> 9, c = k0 & 511;
        int row = rb + lr;                 // global (s,b): s=row>>8, b=row&255
        s8_t a = *(const s8_t*)(h_hi + hidx(dir, row >> 8, c, row & 255));
        s8_t b0 = *(const s8_t*)(nerw + (size_t)lr * 1024 + k0);
        s8_t b1 = *(const s8_t*)(nerw + (size_t)(16 + lr) * 1024 + k0);
        acc[0] = __builtin_amdgcn_mfma_f32_16x16x32_bf16(a, b0, acc[0], 0, 0, 0);
        acc[1] = __builtin_amdgcn_mfma_f32_16x16x32_bf16(a, b1, acc[1], 0, 0, 0);
#pragma unroll
        for (int f = 0; f < 4; ++f) {
            s8_t bf = *(const s8_t*)(fcw + (size_t)(f * 16 + lr) * 1024 + k0);
            accY[f] = __builtin_amdgcn_mfma_f32_16x16x32_bf16(a, bf, accY[f], 0, 0, 0);
        }
        float4 aw0 = *(const float4*)(attn_w + k0);
        float4 aw1 = *(const float4*)(attn_w + k0 + 4);
        sacc += b2f((u16)a[0]) * aw0.x + b2f((u16)a[1]) * aw0.y
              + b2f((u16)a[2]) * aw0.z + b2f((u16)a[3]) * aw0.w
              + b2f((u16)a[4]) * aw1.x + b2f((u16)a[5]) * aw1.y
              + b2f((u16)a[6]) * aw1.z + b2f((u16)a[7]) * aw1.w;
    }
    sacc += __shfl_down(sacc, 32);
    sacc += __shfl_down(sacc, 16);
    if (l < 16) {
        int row = rb + l;
        scores[(row & 255) * S_ + (row >> 8)] = sacc + attn_b[0];
    }
    int lc = l & 15, lr4 = (l >> 4) * 4;
#pragma unroll
    for (int f = 0; f < 2; ++f) {
        int tcol = f * 16 + lc;
        if (tcol < T_) {
            float nb = ner_b[tcol];
#pragma unroll
            for (int r = 0; r < 4; ++r) {
                int row = rb + lr4 + r;
                int s = row >> 8, bb = row & 255;
                em[((size_t)bb * S_ + s) * T_ + tcol] = acc[f][r] + nb;
            }
        }
    }
#pragma unroll
    for (int f = 0; f < 4; ++f) {
        int tcol = f * 16 + lc;
#pragma unroll
        for (int r = 0; r < 4; ++r) {
            int row = rb + lr4 + r;
            y[(size_t)row * O_ + tcol] = accY[f][r];
        }
    }
}

// ---------------- softmax + intent from y (no second h pass) ----------------------
__global__ __launch_bounds__(256) void attn_kernel(const float* scores, const float* y,
                                                   const float* fc_b, float* out)
{
    __shared__ float sc[S_];
    __shared__ float tmp[S_];
    __shared__ float part[4][O_];
    int b = blockIdx.x, tid = threadIdx.x;
    if (tid < S_) sc[tid] = scores[b * S_ + tid];
    __syncthreads();
    if (tid < S_) tmp[tid] = sc[tid];
    __syncthreads();
    for (int st = 64; st > 0; st >>= 1) {
        if (tid < st) tmp[tid] = fmaxf(tmp[tid], tmp[tid + st]);
        __syncthreads();
    }
    float mx = tmp[0];
    __syncthreads();
    if (tid < S_) { sc[tid] = __expf(sc[tid] - mx); tmp[tid] = sc[tid]; }
    __syncthreads();
    for (int st = 64; st > 0; st >>= 1) {
        if (tid < st) tmp[tid] += tmp[tid + st];
        __syncthreads();
    }
    float inv = 1.f / tmp[0];
    __syncthreads();
    if (tid < S_) sc[tid] *= inv;
    __syncthreads();

    int o = tid & 63, q = tid >> 6;
    float acc = 0.f;
    for (int s = q * 32; s < q * 32 + 32; ++s)
        acc += sc[s] * y[((size_t)s * B_ + b) * O_ + o];
    part[q][o] = acc;
    __syncthreads();
    if (tid < O_)
        out[b * O_ + tid] = part[0][tid] + part[1][tid] + part[2][tid] + part[3][tid]
                          + fc_b[tid];
}

// ---------------- CRF forward + numerator fused: res[b] = num - logZ --------------
// 64 threads = two 32-lane segments = two batch elems per block.
__global__ __launch_bounds__(64) void crf2_kernel(const float* em, const int* tags,
                                                  const float* cstart, const float* cend,
                                                  const float* ctrans, float* res)
{
    int l = threadIdx.x & 31;
    int b = blockIdx.x * 2 + (threadIdx.x >> 5);
    bool act = l < T_;
    float E[T_];
#pragma unroll
    for (int i = 0; i < T_; ++i) E[i] = act ? __expf(ctrans[i * T_ + l]) : 0.f;
    const float* eb = em + (size_t)b * S_ * T_;
    float sc = act ? (cstart[l] + eb[l]) : -1e30f;
#pragma unroll 1
    for (int s = 1; s < S_; ++s) {
        float emv = act ? eb[s * T_ + l] : 0.f;
        float m = sc;
#pragma unroll
        for (int off = 16; off; off >>= 1) m = fmaxf(m, __shfl_xor(m, off, 32));
        float e = act ? __expf(sc - m) : 0.f;
        float sum = 0.f;
#pragma unroll
        for (int i = 0; i < T_; ++i) sum += __shfl(e, i, 32) * E[i];
        sc = act ? (m + __logf(sum) + emv) : -1e30f;
    }
    float fin = act ? (sc + cend[l]) : -1e30f;
    float m = fin;
#pragma unroll
    for (int off = 16; off; off >>= 1) m = fmaxf(m, __shfl_xor(m, off, 32));
    float z = act ? __expf(fin - m) : 0.f;
#pragma unroll
    for (int off = 16; off; off >>= 1) z += __shfl_xor(z, off, 32);
    float logZ = m + __logf(z);

    // numerator: each lane handles 4 sequence positions, segment-reduce.
    const int* tg = tags + b * S_;
    float acc = 0.f;
#pragma unroll
    for (int q = 0; q < 4; ++q) {
        int s = l + q * 32;
        int tc = tg[s];
        acc += eb[s * T_ + tc];
        if (s > 0) acc += ctrans[tg[s - 1] * T_ + tc];
    }
#pragma unroll
    for (int off = 16; off; off >>= 1) acc += __shfl_xor(acc, off, 32);
    if (l == 0)
        res[b] = (acc + cstart[tg[0]] + cend[tg[S_ - 1]]) - logZ;
}

// ---------------- final loss ------------------------------------------------------
__global__ __launch_bounds__(256) void loss_kernel(const float* res, float* out)
{
    __shared__ float red[B_];
    int t = threadIdx.x;
    red[t] = res[t];
    __syncthreads();
    for (int st = 128; st > 0; st >>= 1) {
        if (t < st) red[t] += red[t + st];
        __syncthreads();
    }
    if (t == 0) out[16384] = -red[0] / (float)B_;
}

extern "C" void kernel_launch(void* const* d_in, const int* in_sizes, int n_in,
                              void* d_out, int out_size, void* d_ws, size_t ws_size,
                              hipStream_t stream)
{
    const int*   x      = (const int*)  d_in[0];
    const int*   tags   = (const int*)  d_in[1];
    const float* emb    = (const float*)d_in[3];
    const float* wih_f  = (const float*)d_in[4];
    const float* whh_f  = (const float*)d_in[5];
    const float* bih_f  = (const float*)d_in[6];
    const float* bhh_f  = (const float*)d_in[7];
    const float* wih_b  = (const float*)d_in[8];
    const float* whh_b  = (const float*)d_in[9];
    const float* bih_b  = (const float*)d_in[10];
    const float* bhh_b  = (const float*)d_in[11];
    const float* attn_w = (const float*)d_in[12];
    const float* attn_b = (const float*)d_in[13];
    const float* fc_w   = (const float*)d_in[14];
    const float* fc_b   = (const float*)d_in[15];
    const float* ner_w  = (const float*)d_in[16];
    const float* ner_b  = (const float*)d_in[17];
    const float* cstart = (const float*)d_in[18];
    const float* cend   = (const float*)d_in[19];
    const float* ctrans = (const float*)d_in[20];
    float* out = (float*)d_out;

    char* p = (char*)d_ws;
    auto alloc = [&](size_t bytes) { void* r = (void*)p; p += (bytes + 255) & ~(size_t)255; return r; };
    u16* wih_bf  = (u16*)alloc((size_t)3072 * EP_ * 2);
    u16* whh_bf  = (u16*)alloc((size_t)2 * G_ * H_ * 2);
    u16* nerw_bf = (u16*)alloc((size_t)32 * 1024 * 2);
    u16* fcw_bf  = (u16*)alloc((size_t)O_ * 1024 * 2);
    u16* xe      = (u16*)alloc((size_t)BS_ * EP_ * 2);
    u16* h_hi    = (u16*)alloc((size_t)2 * BS_ * H_ * 2);
    unsigned int* flag = (unsigned int*)alloc(16 * 64 * 4);
    unsigned int* xcnt = (unsigned int*)alloc(64);
    float* scores= (float*)alloc((size_t)BS_ * 4);
    float* y     = (float*)alloc((size_t)BS_ * O_ * 4);      // 8 MB
    float* em    = (float*)alloc((size_t)B_ * S_ * T_ * 4);
    float* res   = (float*)alloc(1024);

    hipMemsetAsync(flag, 0, 16 * 64 * 4, stream);
    hipMemsetAsync(xcnt, 0, 64, stream);

    hipLaunchKernelGGL(prep_kernel, dim3(2048), dim3(256), 0, stream,
                       wih_f, wih_b, whh_f, whh_b, ner_w, fc_w,
                       wih_bf, whh_bf, nerw_bf, fcw_bf);
    hipLaunchKernelGGL(gather_kernel, dim3(2048), dim3(256), 0, stream, x, emb, xe);

    void* args[] = { &xe, &wih_bf, &bih_f, &bih_b, &whh_bf, &bhh_f, &bhh_b,
                     &h_hi, &flag, &xcnt };
    hipLaunchCooperativeKernel((const void*)gru_persist, dim3(512), dim3(256), args, 0, stream);

    hipLaunchKernelGGL(rowpass_kernel, dim3(BS_ / 64), dim3(256), 0, stream,
                       h_hi, nerw_bf, ner_b, fcw_bf, attn_w, attn_b, em, scores, y);
    hipLaunchKernelGGL(attn_kernel, dim3(B_), dim3(256), 0, stream, scores, y, fc_b, out);
    hipLaunchKernelGGL(crf2_kernel, dim3(B_ / 2), dim3(64), 0, stream,
                       em, tags, cstart, cend, ctrans, res);
    hipLaunchKernelGGL(loss_kernel, dim3(1), dim3(256), 0, stream, res, out);
}